// Round 12
// baseline (289.015 us; speedup 1.0000x reference)
//
#include <hip/hip_runtime.h>

// HierarchicalChronoFormer forward, MI355X (gfx950).
// B=8, S=4096, D=512, H=8, dk=64, BIN=64, NB=64, T_BINS=1000.

typedef __attribute__((ext_vector_type(8))) short bf16x8;
typedef __attribute__((ext_vector_type(4))) float f32x4;
typedef __attribute__((ext_vector_type(4))) int i32x4;

#define DEVI __device__ __forceinline__

DEVI unsigned short f2bf(float f) {
  union { float f; unsigned u; } v; v.f = f;
  unsigned r = v.u + 0x7FFFu + ((v.u >> 16) & 1u);
  return (unsigned short)(r >> 16);
}
DEVI float bf2f(unsigned short u) {
  union { unsigned u; float f; } v; v.u = ((unsigned)u) << 16; return v.f;
}

#define GLOAD_LDS16(gp, lp) \
  __builtin_amdgcn_global_load_lds((const __attribute__((address_space(1))) void*)(gp), \
                                   (__attribute__((address_space(3))) void*)(lp), 16, 0, 0)

// ---------------- weight transpose-pack + bias concat + time features + er/ea bf16 tables.
// blocks 0..511: Wt; 512: bias concats; 513..520: time; 521..528: er/ea f32->bf16.
struct TPackArgs { const float* s[8]; unsigned short* d[8];
                   const float* bs[6]; float* bd[2];
                   const float* td; const int* x;
                   float* abs_t; float* bin_rel; int* bin_mask; int* last_idx;
                   const float* er; const float* ea;
                   unsigned short* er_bf; unsigned short* ea_bf; };

__global__ __launch_bounds__(256) void k_tpack8(TPackArgs args) {
  __shared__ float shf[8192];                       // 32 KB, aliased per role
  int t = threadIdx.x;
  if (blockIdx.x == 512) {
    for (int i = t; i < 1536; i += 256) {
      int sel = i >> 9, r = i & 511;
      args.bd[0][i] = args.bs[sel][r];
      args.bd[1][i] = args.bs[3 + sel][r];
    }
    return;
  }
  if (blockIdx.x >= 521) {                          // er/ea f32 -> bf16
    int cb = blockIdx.x - 521;                      // 0..7, 125 rows each
    int e0 = cb * 125 * 512;
    int n = 125 * 512;
    for (int i = t; i < n; i += 256) {
      args.er_bf[e0 + i] = f2bf(args.er[e0 + i]);
      args.ea_bf[e0 + i] = f2bf(args.ea[e0 + i]);
    }
    return;
  }
  if (blockIdx.x >= 513) {                          // time features for batch b
    int b = blockIdx.x - 513;
    float* tds = shf;
    int* xs = (int*)(shf + 4096);
    const f32x4* tp = (const f32x4*)(args.td + (size_t)b * 4096);
    const i32x4* xp = (const i32x4*)(args.x + (size_t)b * 4096);
    for (int j = t; j < 1024; j += 256) {
      f32x4 v = tp[j];
#pragma unroll
      for (int c = 0; c < 4; ++c) v[c] = fmaxf(v[c], 0.f);
      *(f32x4*)&tds[j * 4] = v;
      *(i32x4*)&xs[j * 4] = xp[j];
    }
    __syncthreads();
    if (t < 64) {
      int lane = t;
      float s = 0.f;
      for (int i = 0; i < 64; ++i) s += tds[lane * 64 + i];
      float pre = s;
#pragma unroll
      for (int off = 1; off < 64; off <<= 1) {
        float n2 = __shfl_up(pre, off, 64);
        if (lane >= off) pre += n2;
      }
      float a = pre - s;                            // exclusive prefix
      float am = 0.f; int anyv = 0;
      for (int i = 0; i < 64; ++i) {
        a += tds[lane * 64 + i];
        tds[lane * 64 + i] = a;                     // overwrite with cumsum
        if (xs[lane * 64 + i] != 0) { am = fmaxf(am, a); anyv = 1; }
      }
      float prev = __shfl_up(am, 1, 64);
      args.bin_rel[b * 64 + lane] = (lane == 0) ? 0.f : fmaxf(am - prev, 0.f);
      args.bin_mask[b * 64 + lane] = anyv;
      unsigned long long bal = __ballot(anyv != 0);
      if (lane == 0) args.last_idx[b] = max(__popcll(bal) - 1, 0);
    }
    __syncthreads();
    float* out = args.abs_t + (size_t)b * 4096;
    for (int j = t; j < 1024; j += 256)
      *(f32x4*)&out[j * 4] = *(const f32x4*)&tds[j * 4];
    return;
  }
  // weight transpose-pack
  float (*tile)[65] = (float(*)[65])shf;
  int mat = blockIdx.x >> 6;
  int tl = blockIdx.x & 63;
  const float* W = args.s[mat];
  unsigned short* Wt = args.d[mat];
  int n0 = (tl & 7) << 6, k0 = (tl >> 3) << 6;
  int j = t & 63, i0 = t >> 6;
#pragma unroll
  for (int rr = 0; rr < 16; ++rr) {
    int i = rr * 4 + i0;
    tile[i][j] = W[(size_t)(k0 + i) * 512 + n0 + j];
  }
  __syncthreads();
#pragma unroll
  for (int rr = 0; rr < 16; ++rr) {
    int i = rr * 4 + i0;
    Wt[(size_t)(n0 + i) * 512 + k0 + j] = f2bf(tile[j][i]);
  }
}

// ---------------- h = ee[x] (0 if x==0) + er_bf[rb] + ea_bf[ab], bf16 out. 16 tok/block.
__global__ __launch_bounds__(256) void k_embed(const int* __restrict__ x, const float* __restrict__ td,
    const float* __restrict__ abs_t, const float* __restrict__ ee,
    const unsigned short* __restrict__ er_bf, const unsigned short* __restrict__ ea_bf,
    unsigned short* __restrict__ h) {
  int t = threadIdx.x;
  int lane = t & 63;
  int c0 = lane * 8;
#pragma unroll
  for (int it = 0; it < 4; ++it) {
    int tok = blockIdx.x * 16 + it * 4 + (t >> 6);
    int xi = x[tok];
    int rb = (int)td[tok]; rb = min(max(rb, 0), 999);
    int ab = (int)abs_t[tok]; ab = min(max(ab, 0), 999);
    bf16x8 rv = *(const bf16x8*)(er_bf + (size_t)rb * 512 + c0);
    bf16x8 av = *(const bf16x8*)(ea_bf + (size_t)ab * 512 + c0);
    float sf[8];
#pragma unroll
    for (int i = 0; i < 8; ++i)
      sf[i] = bf2f((unsigned short)rv[i]) + bf2f((unsigned short)av[i]);
    if (xi != 0) {
      const f32x4* pe = (const f32x4*)(ee + (size_t)xi * 512 + c0);
      f32x4 e0 = pe[0], e1 = pe[1];
#pragma unroll
      for (int i = 0; i < 4; ++i) { sf[i] += e0[i]; sf[4 + i] += e1[i]; }
    }
    bf16x8 o;
#pragma unroll
    for (int i = 0; i < 8; ++i) o[i] = (short)f2bf(sf[i]);
    *(bf16x8*)(h + (size_t)tok * 512 + c0) = o;
  }
}

// ---------------- swizzle helpers
DEVI bf16x8 lds_frag32(const unsigned short* buf, int r, int g) {
  int sr = r >> 1;
  int slot = (((r & 1) << 2) | g) ^ (sr & 7);
  return *(const bf16x8*)&buf[sr * 64 + slot * 8];
}
DEVI bf16x8 lds_frag64(const unsigned short* buf, int row, int c) {
  return *(const bf16x8*)&buf[row * 64 + ((c ^ (row & 7)) << 3)];
}

// ---------------- big GEMM (QKV): 128x256 tile, 8 waves of 64x64 (r11 best: 59.5us).
__global__ __launch_bounds__(512, 4) void k_gemm256(const unsigned short* __restrict__ A,
    const unsigned short* __restrict__ Wt, const float* __restrict__ bias,
    unsigned short* __restrict__ Cout, int N, int tiles_n) {
  __shared__ unsigned short As[128 * 64];   // 16 KB
  __shared__ unsigned short Bs[256 * 64];   // 32 KB
  int bid = blockIdx.x;
  { int q = (int)gridDim.x >> 3; bid = (bid & 7) * q + (bid >> 3); }  // grid %8==0
  int by = bid / tiles_n, bx = bid % tiles_n;
  int m0 = by << 7, n0 = bx << 8;
  int t = threadIdx.x;
  int lane = t & 63, w = t >> 6;
  int wm = w >> 2, wn = w & 3;
  int l15 = lane & 15, l4 = lane >> 4;

  f32x4 acc[4][4] = {};
  for (int k0 = 0; k0 < 512; k0 += 64) {
    __syncthreads();
#pragma unroll
    for (int l = 0; l < 2; ++l) {
      int pos = l * 512 + t;
      int row = pos >> 3, g = (pos & 7) ^ (row & 7);
      GLOAD_LDS16(&A[(size_t)(m0 + row) * 512 + k0 + g * 8], &As[pos * 8]);
    }
#pragma unroll
    for (int l = 0; l < 4; ++l) {
      int pos = l * 512 + t;
      int row = pos >> 3, g = (pos & 7) ^ (row & 7);
      GLOAD_LDS16(&Wt[(size_t)(n0 + row) * 512 + k0 + g * 8], &Bs[pos * 8]);
    }
    __syncthreads();
#pragma unroll
    for (int ks = 0; ks < 2; ++ks) {
      bf16x8 af[4], bb[4];
#pragma unroll
      for (int i = 0; i < 4; ++i) {
        af[i] = lds_frag64(As, wm * 64 + i * 16 + l15, ks * 4 + l4);
        bb[i] = lds_frag64(Bs, wn * 64 + i * 16 + l15, ks * 4 + l4);
      }
      __builtin_amdgcn_s_setprio(1);
#pragma unroll
      for (int i = 0; i < 4; ++i)
#pragma unroll
        for (int j = 0; j < 4; ++j)
          acc[i][j] = __builtin_amdgcn_mfma_f32_16x16x32_bf16(af[i], bb[j], acc[i][j], 0, 0, 0);
      __builtin_amdgcn_s_setprio(0);
    }
  }
#pragma unroll
  for (int i = 0; i < 4; ++i) {
    int rowb = m0 + wm * 64 + i * 16 + (l4 << 2);
#pragma unroll
    for (int j = 0; j < 4; ++j) {
      int col = n0 + wn * 64 + j * 16 + l15;
      float bv = bias[col];
#pragma unroll
      for (int r = 0; r < 4; ++r)
        Cout[(size_t)(rowb + r) * N + col] = f2bf(acc[i][j][r] + bv);
    }
  }
}

// ---------------- fused out-proj + LN + masked pool: BM=128, BN=512, BK=32 (r10 best).
__global__ __launch_bounds__(512, 2) void k_oproj(const unsigned short* __restrict__ ctx,
    const unsigned short* __restrict__ WoT, const float* __restrict__ bo,
    const int* __restrict__ x, const float* __restrict__ g, const float* __restrict__ bt,
    unsigned short* __restrict__ bin_repr) {
  __shared__ unsigned short ldsA[4][128 * 32];
  __shared__ unsigned short ldsB[2][512 * 32];
  int bid = blockIdx.x;
  { int q = (int)gridDim.x >> 3; bid = (bid & 7) * q + (bid >> 3); }
  int m0 = bid << 7;
  int t = threadIdx.x;
  int lane = t & 63, w = t >> 6;
  int l15 = lane & 15, l4 = lane >> 4;

  auto stageA = [&](int kt) {
    int k0 = kt << 5;
    unsigned short* dst = &ldsA[kt & 3][0];
    int pos = t;
    int sr = pos >> 3, slot = pos & 7;
    int gp = slot ^ (sr & 7);
    int row = sr * 2 + (gp >> 2);
    GLOAD_LDS16(&ctx[(size_t)(m0 + row) * 512 + k0 + (gp & 3) * 8], dst + pos * 8);
  };
  auto stageB = [&](int kt) {
    int k0 = kt << 5;
    unsigned short* dst = &ldsB[kt & 1][0];
#pragma unroll
    for (int l = 0; l < 4; ++l) {
      int pos = l * 512 + t;
      int sr = pos >> 3, slot = pos & 7;
      int gp = slot ^ (sr & 7);
      int row = sr * 2 + (gp >> 2);
      GLOAD_LDS16(&WoT[(size_t)row * 512 + k0 + (gp & 3) * 8], dst + pos * 8);
    }
  };

  f32x4 acc[8][4] = {};
  stageB(0); stageA(0); stageA(1); stageA(2); stageB(1);

  for (int kt = 0; kt < 16; ++kt) {
    if (kt == 0)      asm volatile("s_waitcnt vmcnt(6)" ::: "memory");
    else if (kt < 14) asm volatile("s_waitcnt vmcnt(1)" ::: "memory");
    else              asm volatile("s_waitcnt vmcnt(0)" ::: "memory");
    __builtin_amdgcn_s_barrier();
    const unsigned short* As = &ldsA[kt & 3][0];
    const unsigned short* Bs = &ldsB[kt & 1][0];

    bf16x8 af[4], bb[4];
#pragma unroll
    for (int i = 0; i < 4; ++i) af[i] = lds_frag32(As, i * 16 + l15, l4);
#pragma unroll
    for (int j = 0; j < 4; ++j) bb[j] = lds_frag32(Bs, w * 64 + j * 16 + l15, l4);
    if (kt >= 1 && kt <= 14) stageB(kt + 1);
    __builtin_amdgcn_s_barrier();
    asm volatile("s_waitcnt lgkmcnt(0)" ::: "memory");
    __builtin_amdgcn_sched_barrier(0);
    __builtin_amdgcn_s_setprio(1);
#pragma unroll
    for (int i = 0; i < 4; ++i)
#pragma unroll
      for (int j = 0; j < 4; ++j)
        acc[i][j] = __builtin_amdgcn_mfma_f32_16x16x32_bf16(af[i], bb[j], acc[i][j], 0, 0, 0);
    __builtin_amdgcn_s_setprio(0);

    bf16x8 ah[4];
#pragma unroll
    for (int i = 0; i < 4; ++i) ah[i] = lds_frag32(As, 64 + i * 16 + l15, l4);
    if (kt <= 12) stageA(kt + 3);
    __builtin_amdgcn_s_barrier();
    asm volatile("s_waitcnt lgkmcnt(0)" ::: "memory");
    __builtin_amdgcn_sched_barrier(0);
    __builtin_amdgcn_s_setprio(1);
#pragma unroll
    for (int i = 0; i < 4; ++i)
#pragma unroll
      for (int j = 0; j < 4; ++j)
        acc[4 + i][j] = __builtin_amdgcn_mfma_f32_16x16x32_bf16(ah[i], bb[j], acc[4 + i][j], 0, 0, 0);
    __builtin_amdgcn_s_setprio(0);
  }

  __syncthreads();
  float* red   = (float*)&ldsA[0][0];    // [128][9]
  float* meanL = red + 128 * 9;
  float* rstdL = meanL + 128;
  int*   valL  = (int*)(rstdL + 128);
  int*   cntL  = valL + 128;

  int cols[4]; float bov[4], gv[4], bv[4];
#pragma unroll
  for (int j = 0; j < 4; ++j) {
    cols[j] = w * 64 + j * 16 + l15;
    bov[j] = bo[cols[j]]; gv[j] = g[cols[j]]; bv[j] = bt[cols[j]];
  }
  if (t < 128) {
    int v = (x[m0 + t] != 0) ? 1 : 0;
    valL[t] = v;
    unsigned long long bal = __ballot(v != 0);
    if ((t & 63) == 0) cntL[t >> 6] = __popcll(bal);
  }
#pragma unroll
  for (int i = 0; i < 8; ++i)
#pragma unroll
    for (int r = 0; r < 4; ++r) {
      float s = (acc[i][0][r] + bov[0]) + (acc[i][1][r] + bov[1]) +
                (acc[i][2][r] + bov[2]) + (acc[i][3][r] + bov[3]);
#pragma unroll
      for (int off = 1; off < 16; off <<= 1) s += __shfl_xor(s, off, 64);
      if (l15 == 0) red[(i * 16 + l4 * 4 + r) * 9 + w] = s;
    }
  __syncthreads();
  if (t < 128) {
    float m = 0.f;
#pragma unroll
    for (int ww = 0; ww < 8; ++ww) m += red[t * 9 + ww];
    meanL[t] = m * (1.f / 512.f);
  }
  __syncthreads();
#pragma unroll
  for (int i = 0; i < 8; ++i)
#pragma unroll
    for (int r = 0; r < 4; ++r) {
      float m = meanL[i * 16 + l4 * 4 + r];
      float s = 0.f;
#pragma unroll
      for (int j = 0; j < 4; ++j) { float d = acc[i][j][r] + bov[j] - m; s += d * d; }
#pragma unroll
      for (int off = 1; off < 16; off <<= 1) s += __shfl_xor(s, off, 64);
      if (l15 == 0) red[(i * 16 + l4 * 4 + r) * 9 + w] = s;
    }
  __syncthreads();
  if (t < 128) {
    float vsum = 0.f;
#pragma unroll
    for (int ww = 0; ww < 8; ++ww) vsum += red[t * 9 + ww];
    rstdL[t] = rsqrtf(vsum * (1.f / 512.f) + 1e-5f);
  }
  __syncthreads();
  float p0[4] = {0.f, 0.f, 0.f, 0.f}, p1[4] = {0.f, 0.f, 0.f, 0.f};
#pragma unroll
  for (int i = 0; i < 8; ++i)
#pragma unroll
    for (int r = 0; r < 4; ++r) {
      int row = i * 16 + l4 * 4 + r;
      if (valL[row]) {
        float m = meanL[row], rs = rstdL[row];
#pragma unroll
        for (int j = 0; j < 4; ++j) {
          float y = (acc[i][j][r] + bov[j] - m) * rs * gv[j] + bv[j];
          if (i < 4) p0[j] += y; else p1[j] += y;
        }
      }
    }
#pragma unroll
  for (int j = 0; j < 4; ++j) {
    p0[j] += __shfl_xor(p0[j], 16, 64); p0[j] += __shfl_xor(p0[j], 32, 64);
    p1[j] += __shfl_xor(p1[j], 16, 64); p1[j] += __shfl_xor(p1[j], 32, 64);
  }
  float d0 = 1.f / fmaxf((float)cntL[0], 1.f);
  float d1 = 1.f / fmaxf((float)cntL[1], 1.f);
  if (l4 == 0) {
    int binr = (m0 >> 6);
#pragma unroll
    for (int j = 0; j < 4; ++j) {
      bin_repr[(size_t)binr * 512 + cols[j]]       = f2bf(p0[j] * d0);
      bin_repr[(size_t)(binr + 1) * 512 + cols[j]] = f2bf(p1[j] * d1);
    }
  }
}

// ---------------- small GEMM (inter qkv2): 128x128 tile, reg-staged padded LDS.
__global__ __launch_bounds__(256) void k_gemm(const unsigned short* __restrict__ A,
    const unsigned short* __restrict__ Wt, const float* __restrict__ bias,
    unsigned short* __restrict__ Cout, int N, int tiles_n) {
  __shared__ unsigned short As[128 * 72];
  __shared__ unsigned short Bs[128 * 72];
  int bx = blockIdx.x % tiles_n;
  int by = blockIdx.x / tiles_n;
  int m0 = by << 7, n0 = bx << 7;
  int t = threadIdx.x;
  int lane = t & 63, w = t >> 6;
  int wm = w >> 1, wn = w & 1;
  f32x4 acc[4][4] = {};
  for (int k0 = 0; k0 < 512; k0 += 64) {
    __syncthreads();
#pragma unroll
    for (int i = 0; i < 4; ++i) {
      int idx = t + i * 256;
      int row = idx >> 3, seg = idx & 7;
      *(bf16x8*)&As[row * 72 + seg * 8] = *(const bf16x8*)&A[(size_t)(m0 + row) * 512 + k0 + seg * 8];
      *(bf16x8*)&Bs[row * 72 + seg * 8] = *(const bf16x8*)&Wt[(size_t)(n0 + row) * 512 + k0 + seg * 8];
    }
    __syncthreads();
#pragma unroll
    for (int ks = 0; ks < 2; ++ks) {
      bf16x8 af[4], bb[4];
#pragma unroll
      for (int i = 0; i < 4; ++i) {
        af[i] = *(const bf16x8*)&As[(wm * 64 + i * 16 + (lane & 15)) * 72 + ks * 32 + (lane >> 4) * 8];
        bb[i] = *(const bf16x8*)&Bs[(wn * 64 + i * 16 + (lane & 15)) * 72 + ks * 32 + (lane >> 4) * 8];
      }
#pragma unroll
      for (int i = 0; i < 4; ++i)
#pragma unroll
        for (int j = 0; j < 4; ++j)
          acc[i][j] = __builtin_amdgcn_mfma_f32_16x16x32_bf16(af[i], bb[j], acc[i][j], 0, 0, 0);
    }
  }
#pragma unroll
  for (int i = 0; i < 4; ++i) {
    int rowb = m0 + wm * 64 + i * 16 + ((lane >> 4) << 2);
#pragma unroll
    for (int j = 0; j < 4; ++j) {
      int col = n0 + wn * 64 + j * 16 + (lane & 15);
      float bv = bias[col];
#pragma unroll
      for (int r = 0; r < 4; ++r)
        Cout[(size_t)(rowb + r) * N + col] = f2bf(acc[i][j][r] + bv);
    }
  }
}

// ---------------- intra attention; block = 4 heads of one 64-token bin (2 blocks/bin).
__global__ __launch_bounds__(256) void k_attn(const unsigned short* __restrict__ qkv,
    const float* __restrict__ td, const int* __restrict__ validv,
    const float* __restrict__ temb, unsigned short* __restrict__ ctx) {
  __shared__ float bias_s[4][64];
  __shared__ int valid_s[64];
  __shared__ unsigned short P_s[4][64][72];
  __shared__ unsigned short Vt_s[4][64][72];
  int blk = blockIdx.x >> 1, hg = blockIdx.x & 1;
  int t = threadIdx.x, hl = t >> 6, lane = t & 63;
  int h = hg * 4 + hl;
  size_t base = (size_t)blk * 64;
  if (t < 64) {
    valid_s[t] = (validv[base + t] != 0) ? 1 : 0;
    int tb = (int)td[base + t];
    tb = min(max(tb, 0), 999);
#pragma unroll
    for (int hh = 0; hh < 4; ++hh) bias_s[hh][t] = temb[tb * 8 + hg * 4 + hh];
  }
  {
    const unsigned short* vp = qkv + (base + lane) * 1536 + 1024 + h * 64;
#pragma unroll
    for (int f8 = 0; f8 < 8; ++f8) {
      bf16x8 v8 = *(const bf16x8*)(vp + f8 * 8);
#pragma unroll
      for (int j = 0; j < 8; ++j) Vt_s[hl][f8 * 8 + j][lane] = (unsigned short)v8[j];
    }
  }
  __syncthreads();
  bf16x8 qa[2][4], kb[2][4];
#pragma unroll
  for (int ks = 0; ks < 2; ++ks)
#pragma unroll
    for (int i = 0; i < 4; ++i) {
      int row = i * 16 + (lane & 15);
      int kk = ks * 32 + (lane >> 4) * 8;
      qa[ks][i] = *(const bf16x8*)&qkv[(base + row) * 1536 + h * 64 + kk];
      kb[ks][i] = *(const bf16x8*)&qkv[(base + row) * 1536 + 512 + h * 64 + kk];
    }
  f32x4 acc[4][4] = {};
#pragma unroll
  for (int ks = 0; ks < 2; ++ks)
#pragma unroll
    for (int i = 0; i < 4; ++i)
#pragma unroll
      for (int j = 0; j < 4; ++j)
        acc[i][j] = __builtin_amdgcn_mfma_f32_16x16x32_bf16(qa[ks][i], kb[ks][j], acc[i][j], 0, 0, 0);
  float invs[4][4];
#pragma unroll
  for (int i = 0; i < 4; ++i) {
#pragma unroll
    for (int r = 0; r < 4; ++r) {
      float sv[4];
#pragma unroll
      for (int j = 0; j < 4; ++j) {
        int key = j * 16 + (lane & 15);
        float s = acc[i][j][r] * 0.125f;
        sv[j] = valid_s[key] ? (s + bias_s[hl][key]) : -1e9f;
      }
      float m = fmaxf(fmaxf(sv[0], sv[1]), fmaxf(sv[2], sv[3]));
#pragma unroll
      for (int off = 1; off < 16; off <<= 1) m = fmaxf(m, __shfl_xor(m, off, 64));
      float p[4], sum = 0.f;
#pragma unroll
      for (int j = 0; j < 4; ++j) { p[j] = __expf(sv[j] - m); sum += p[j]; }
#pragma unroll
      for (int off = 1; off < 16; off <<= 1) sum += __shfl_xor(sum, off, 64);
      invs[i][r] = 1.f / sum;
      int row = i * 16 + ((lane >> 4) << 2) + r;
#pragma unroll
      for (int j = 0; j < 4; ++j) P_s[hl][row][j * 16 + (lane & 15)] = f2bf(p[j]);
    }
  }
  __syncthreads();
  f32x4 acc2[4][4] = {};
#pragma unroll
  for (int ks = 0; ks < 2; ++ks) {
    bf16x8 pa[4], vb[4];
    int kk = ks * 32 + (lane >> 4) * 8;
#pragma unroll
    for (int i = 0; i < 4; ++i) {
      pa[i] = *(const bf16x8*)&P_s[hl][i * 16 + (lane & 15)][kk];
      vb[i] = *(const bf16x8*)&Vt_s[hl][i * 16 + (lane & 15)][kk];
    }
#pragma unroll
    for (int i = 0; i < 4; ++i)
#pragma unroll
      for (int j = 0; j < 4; ++j)
        acc2[i][j] = __builtin_amdgcn_mfma_f32_16x16x32_bf16(pa[i], vb[j], acc2[i][j], 0, 0, 0);
  }
  unsigned short* scr = &Vt_s[hl][0][0];
#pragma unroll
  for (int i = 0; i < 4; ++i)
#pragma unroll
    for (int j = 0; j < 4; ++j)
#pragma unroll
      for (int r = 0; r < 4; ++r)
        scr[(i * 16 + ((lane >> 4) << 2) + r) * 72 + j * 16 + (lane & 15)] =
            f2bf(acc2[i][j][r] * invs[i][r]);
#pragma unroll
  for (int p = 0; p < 8; ++p) {
    int rl = p * 8 + (lane >> 3);
    bf16x8 vv = *(const bf16x8*)&scr[rl * 72 + (lane & 7) * 8];
    *(bf16x8*)&ctx[(base + rl) * 512 + h * 64 + (lane & 7) * 8] = vv;
  }
}

// ---------------- fused inter attention + last-row proj + LN + MLP + sigmoid.
// One block per batch (8 blocks, 8 waves = 8 heads). Only h_inter[b, last_idx[b]] is
// consumed downstream -> proj/LN/MLP on that single row.
__global__ __launch_bounds__(512) void k_inter2(const unsigned short* __restrict__ qkv,
    const float* __restrict__ brel, const int* __restrict__ bmask,
    const float* __restrict__ temb, const int* __restrict__ last_idx,
    const float* __restrict__ Wo, const float* __restrict__ bo,
    const float* __restrict__ g, const float* __restrict__ bt,
    const float* __restrict__ w1, const float* __restrict__ b1,
    const float* __restrict__ w2, const float* __restrict__ b2,
    float* __restrict__ outp) {
  __shared__ unsigned short Vt[8][64][72];
  __shared__ unsigned short PsCtx[8 * 64 * 72];     // Ps slots, then ctx[64][520] overlay
  __shared__ float bias_s[8][64];
  __shared__ int valid_s[64];
  __shared__ float rowf[512];
  __shared__ float redA[8];
  __shared__ float redB[8];
  int b = blockIdx.x;
  int t = threadIdx.x, w = t >> 6, lane = t & 63;
  int l15 = lane & 15, l4 = lane >> 4;
  size_t base = (size_t)b * 64;

  if (t < 64) {
    valid_s[t] = (bmask[base + t] != 0) ? 1 : 0;
    int tb = (int)brel[base + t];
    tb = min(max(tb, 0), 999);
#pragma unroll
    for (int hh = 0; hh < 8; ++hh) bias_s[hh][t] = temb[tb * 8 + hh];
  }
  {  // stage V transposed for head w
    const unsigned short* vp = qkv + (base + lane) * 1536 + 1024 + w * 64;
#pragma unroll
    for (int f8 = 0; f8 < 8; ++f8) {
      bf16x8 v8 = *(const bf16x8*)(vp + f8 * 8);
#pragma unroll
      for (int j = 0; j < 8; ++j) Vt[w][f8 * 8 + j][lane] = (unsigned short)v8[j];
    }
  }
  __syncthreads();

  bf16x8 qa[2][4], kb[2][4];
#pragma unroll
  for (int ks = 0; ks < 2; ++ks)
#pragma unroll
    for (int i = 0; i < 4; ++i) {
      int row = i * 16 + l15;
      int kk = ks * 32 + l4 * 8;
      qa[ks][i] = *(const bf16x8*)&qkv[(base + row) * 1536 + w * 64 + kk];
      kb[ks][i] = *(const bf16x8*)&qkv[(base + row) * 1536 + 512 + w * 64 + kk];
    }
  f32x4 acc[4][4] = {};
#pragma unroll
  for (int ks = 0; ks < 2; ++ks)
#pragma unroll
    for (int i = 0; i < 4; ++i)
#pragma unroll
      for (int j = 0; j < 4; ++j)
        acc[i][j] = __builtin_amdgcn_mfma_f32_16x16x32_bf16(qa[ks][i], kb[ks][j], acc[i][j], 0, 0, 0);

  unsigned short* Psw = &PsCtx[w * 64 * 72];
  float invs[4][4];
#pragma unroll
  for (int i = 0; i < 4; ++i) {
#pragma unroll
    for (int r = 0; r < 4; ++r) {
      float sv[4];
#pragma unroll
      for (int j = 0; j < 4; ++j) {
        int key = j * 16 + l15;
        float s = acc[i][j][r] * 0.125f;
        sv[j] = valid_s[key] ? (s + bias_s[w][key]) : -1e9f;
      }
      float m = fmaxf(fmaxf(sv[0], sv[1]), fmaxf(sv[2], sv[3]));
#pragma unroll
      for (int off = 1; off < 16; off <<= 1) m = fmaxf(m, __shfl_xor(m, off, 64));
      float p[4], sum = 0.f;
#pragma unroll
      for (int j = 0; j < 4; ++j) { p[j] = __expf(sv[j] - m); sum += p[j]; }
#pragma unroll
      for (int off = 1; off < 16; off <<= 1) sum += __shfl_xor(sum, off, 64);
      invs[i][r] = 1.f / sum;
      int row = i * 16 + l4 * 4 + r;
#pragma unroll
      for (int j = 0; j < 4; ++j) Psw[row * 72 + j * 16 + l15] = f2bf(p[j]);
    }
  }

  f32x4 acc2[4][4] = {};
#pragma unroll
  for (int ks = 0; ks < 2; ++ks) {
    bf16x8 pa[4], vb[4];
    int kk = ks * 32 + l4 * 8;
#pragma unroll
    for (int i = 0; i < 4; ++i) {
      pa[i] = *(const bf16x8*)&Psw[(i * 16 + l15) * 72 + kk];
      vb[i] = *(const bf16x8*)&Vt[w][i * 16 + l15][kk];
    }
#pragma unroll
    for (int i = 0; i < 4; ++i)
#pragma unroll
      for (int j = 0; j < 4; ++j)
        acc2[i][j] = __builtin_amdgcn_mfma_f32_16x16x32_bf16(pa[i], vb[j], acc2[i][j], 0, 0, 0);
  }

  __syncthreads();
  unsigned short* ctxl = PsCtx;                     // ctx[64][520] overlay
#pragma unroll
  for (int i = 0; i < 4; ++i)
#pragma unroll
    for (int j = 0; j < 4; ++j)
#pragma unroll
      for (int r = 0; r < 4; ++r)
        ctxl[(i * 16 + l4 * 4 + r) * 520 + w * 64 + j * 16 + l15] =
            f2bf(acc2[i][j][r] * invs[i][r]);
  __syncthreads();

  // proj of row last_idx: out[n] = bo[n] + sum_k ctx[k] * Wo[k][n]  (Wo f32 k-major)
  int li = last_idx[b];
  const unsigned short* crow = &ctxl[li * 520];
  float pacc = bo[t];
  for (int k = 0; k < 512; k += 4) {
    float c0 = bf2f(crow[k]),     c1 = bf2f(crow[k + 1]);
    float c2 = bf2f(crow[k + 2]), c3 = bf2f(crow[k + 3]);
    pacc += c0 * Wo[(size_t)k * 512 + t]       + c1 * Wo[(size_t)(k + 1) * 512 + t]
          + c2 * Wo[(size_t)(k + 2) * 512 + t] + c3 * Wo[(size_t)(k + 3) * 512 + t];
  }
  // LN over the 512-vec
  float s = pacc;
#pragma unroll
  for (int off = 1; off < 64; off <<= 1) s += __shfl_xor(s, off, 64);
  if (lane == 0) redA[w] = s;
  __syncthreads();
  float tot = 0.f;
#pragma unroll
  for (int ww = 0; ww < 8; ++ww) tot += redA[ww];
  float mean = tot * (1.f / 512.f);
  float d = pacc - mean;
  float vs = d * d;
#pragma unroll
  for (int off = 1; off < 64; off <<= 1) vs += __shfl_xor(vs, off, 64);
  if (lane == 0) redB[w] = vs;
  __syncthreads();
  float vtot = 0.f;
#pragma unroll
  for (int ww = 0; ww < 8; ++ww) vtot += redB[ww];
  float rstd = rsqrtf(vtot * (1.f / 512.f) + 1e-5f);
  rowf[t] = d * rstd * g[t] + bt[t];
  __syncthreads();
  // MLP: hidden j (t<256), then reduce
  float hv = 0.f;
  if (t < 256) {
    float a1 = b1[t];
    for (int k = 0; k < 512; ++k) a1 += rowf[k] * w1[(size_t)k * 256 + t];
    hv = fmaxf(a1, 0.f) * w2[t];
  }
#pragma unroll
  for (int off = 1; off < 64; off <<= 1) hv += __shfl_xor(hv, off, 64);
  if (lane == 0) redA[w] = hv;
  __syncthreads();
  if (t == 0) {
    float o = redA[0] + redA[1] + redA[2] + redA[3] + redA[4] + redA[5] + redA[6] + redA[7] + b2[0];
    outp[b] = 1.f / (1.f + __expf(-o));
  }
}

extern "C" void kernel_launch(void* const* d_in, const int* in_sizes, int n_in,
                              void* d_out, int out_size, void* d_ws, size_t ws_size,
                              hipStream_t stream) {
  const int*   x    = (const int*)d_in[0];
  const float* td   = (const float*)d_in[1];
  const float* ee   = (const float*)d_in[2];
  const float* er   = (const float*)d_in[3];
  const float* ea   = (const float*)d_in[4];
  const float* iq_w = (const float*)d_in[5];  const float* iq_b = (const float*)d_in[6];
  const float* ik_w = (const float*)d_in[7];  const float* ik_b = (const float*)d_in[8];
  const float* iv_w = (const float*)d_in[9];  const float* iv_b = (const float*)d_in[10];
  const float* io_w = (const float*)d_in[11]; const float* io_b = (const float*)d_in[12];
  const float* eq_w = (const float*)d_in[13]; const float* eq_b = (const float*)d_in[14];
  const float* ek_w = (const float*)d_in[15]; const float* ek_b = (const float*)d_in[16];
  const float* ev_w = (const float*)d_in[17]; const float* ev_b = (const float*)d_in[18];
  const float* eo_w = (const float*)d_in[19]; const float* eo_b = (const float*)d_in[20];
  const float* i_temb = (const float*)d_in[21];
  const float* e_temb = (const float*)d_in[22];
  const float* i_g  = (const float*)d_in[23]; const float* i_bt = (const float*)d_in[24];
  const float* e_g  = (const float*)d_in[25]; const float* e_bt = (const float*)d_in[26];
  const float* w1   = (const float*)d_in[27]; const float* b1   = (const float*)d_in[28];
  const float* w2   = (const float*)d_in[29]; const float* b2   = (const float*)d_in[30];

  char* ws = (char*)d_ws;
  size_t off = 0;
  auto alloc = [&](size_t nb) { size_t r = off; off += (nb + 255) & ~(size_t)255; return r; };
  float* abs_t    = (float*)(ws + alloc((size_t)32768 * 4));
  float* bin_rel  = (float*)(ws + alloc(512 * 4));
  int*   bin_mask = (int*)(ws + alloc(512 * 4));
  int*   last_idx = (int*)(ws + alloc(64));
  unsigned short* wqkv_i = (unsigned short*)(ws + alloc((size_t)1536 * 512 * 2));
  unsigned short* wo_i   = (unsigned short*)(ws + alloc((size_t)512 * 512 * 2));
  unsigned short* wqkv_e = (unsigned short*)(ws + alloc((size_t)1536 * 512 * 2));
  unsigned short* wo_e   = (unsigned short*)(ws + alloc((size_t)512 * 512 * 2));
  float* bqkv_i = (float*)(ws + alloc(1536 * 4));
  float* bqkv_e = (float*)(ws + alloc(1536 * 4));
  unsigned short* er_bf = (unsigned short*)(ws + alloc((size_t)1000 * 512 * 2));
  unsigned short* ea_bf = (unsigned short*)(ws + alloc((size_t)1000 * 512 * 2));
  unsigned short* hbuf = (unsigned short*)(ws + alloc((size_t)32768 * 512 * 2));   // h, then ctx
  unsigned short* qkvbuf = (unsigned short*)(ws + alloc((size_t)32768 * 1536 * 2));
  unsigned short* bin_repr = (unsigned short*)(ws + alloc((size_t)512 * 512 * 2));
  unsigned short* qkv2 = (unsigned short*)(ws + alloc((size_t)512 * 1536 * 2));

  // 1. pack weights + bias concats + time features + er/ea bf16 tables (one launch)
  TPackArgs tp;
  tp.s[0] = iq_w; tp.d[0] = wqkv_i;
  tp.s[1] = ik_w; tp.d[1] = wqkv_i + (size_t)512 * 512;
  tp.s[2] = iv_w; tp.d[2] = wqkv_i + (size_t)1024 * 512;
  tp.s[3] = io_w; tp.d[3] = wo_i;
  tp.s[4] = eq_w; tp.d[4] = wqkv_e;
  tp.s[5] = ek_w; tp.d[5] = wqkv_e + (size_t)512 * 512;
  tp.s[6] = ev_w; tp.d[6] = wqkv_e + (size_t)1024 * 512;
  tp.s[7] = eo_w; tp.d[7] = wo_e;
  tp.bs[0] = iq_b; tp.bs[1] = ik_b; tp.bs[2] = iv_b;
  tp.bs[3] = eq_b; tp.bs[4] = ek_b; tp.bs[5] = ev_b;
  tp.bd[0] = bqkv_i; tp.bd[1] = bqkv_e;
  tp.td = td; tp.x = x;
  tp.abs_t = abs_t; tp.bin_rel = bin_rel; tp.bin_mask = bin_mask; tp.last_idx = last_idx;
  tp.er = er; tp.ea = ea; tp.er_bf = er_bf; tp.ea_bf = ea_bf;
  k_tpack8<<<529, 256, 0, stream>>>(tp);

  // 2. embeddings -> h
  k_embed<<<2048, 256, 0, stream>>>(x, td, abs_t, ee, er_bf, ea_bf, hbuf);

  // 3. intra path
  k_gemm256<<<256 * 6, 512, 0, stream>>>(hbuf, wqkv_i, bqkv_i, qkvbuf, 1536, 6);
  k_attn<<<1024, 256, 0, stream>>>(qkvbuf, td, x, i_temb, hbuf);                   // ctx -> hbuf
  k_oproj<<<256, 512, 0, stream>>>(hbuf, wo_i, io_b, x, i_g, i_bt, bin_repr);      // proj+LN+pool

  // 4. inter path: qkv2 GEMM, then fused attn+proj-row+LN+MLP+sigmoid
  k_gemm<<<4 * 12, 256, 0, stream>>>(bin_repr, wqkv_e, bqkv_e, qkv2, 1536, 12);
  k_inter2<<<8, 512, 0, stream>>>(qkv2, bin_rel, bin_mask, e_temb, last_idx,
                                  eo_w, eo_b, e_g, e_bt, w1, b1, w2, b2, (float*)d_out);
}

// Round 13
// 216.137 us; speedup vs baseline: 1.3372x; 1.3372x over previous
//
#include <hip/hip_runtime.h>

// HierarchicalChronoFormer forward, MI355X (gfx950).
// B=8, S=4096, D=512, H=8, dk=64, BIN=64, NB=64, T_BINS=1000.

typedef __attribute__((ext_vector_type(8))) short bf16x8;
typedef __attribute__((ext_vector_type(4))) float f32x4;
typedef __attribute__((ext_vector_type(4))) int i32x4;
typedef __attribute__((ext_vector_type(4))) unsigned short u16x4;

#define DEVI __device__ __forceinline__

DEVI unsigned short f2bf(float f) {
  union { float f; unsigned u; } v; v.f = f;
  unsigned r = v.u + 0x7FFFu + ((v.u >> 16) & 1u);
  return (unsigned short)(r >> 16);
}
DEVI float bf2f(unsigned short u) {
  union { unsigned u; float f; } v; v.u = ((unsigned)u) << 16; return v.f;
}

#define GLOAD_LDS16(gp, lp) \
  __builtin_amdgcn_global_load_lds((const __attribute__((address_space(1))) void*)(gp), \
                                   (__attribute__((address_space(3))) void*)(lp), 16, 0, 0)

// ---------------- weight transpose-pack + bias concat + time features + er/ea bf16 tables.
// blocks 0..511: Wt; 512: bias concats; 513..520: time; 521..648: er/ea f32->bf16 (128 blks).
struct TPackArgs { const float* s[8]; unsigned short* d[8];
                   const float* bs[6]; float* bd[2];
                   const float* td; const int* x;
                   float* abs_t; float* bin_rel; int* bin_mask; int* last_idx;
                   const float* er; const float* ea;
                   unsigned short* er_bf; unsigned short* ea_bf; };

__global__ __launch_bounds__(256) void k_tpack8(TPackArgs args) {
  __shared__ float shf[8192];                       // 32 KB, aliased per role
  int t = threadIdx.x;
  if (blockIdx.x == 512) {
    for (int i = t; i < 1536; i += 256) {
      int sel = i >> 9, r = i & 511;
      args.bd[0][i] = args.bs[sel][r];
      args.bd[1][i] = args.bs[3 + sel][r];
    }
    return;
  }
  if (blockIdx.x >= 521) {                          // er/ea f32 -> bf16, vectorized
    int cb = blockIdx.x - 521;                      // 0..127; 1000 f32x4 chunks each
    const f32x4* er4 = (const f32x4*)args.er;
    const f32x4* ea4 = (const f32x4*)args.ea;
    u16x4* erb4 = (u16x4*)args.er_bf;
    u16x4* eab4 = (u16x4*)args.ea_bf;
    int base = cb * 1000;
    for (int i = t; i < 1000; i += 256) {
      f32x4 vr = er4[base + i];
      f32x4 va = ea4[base + i];
      u16x4 or_, oa_;
#pragma unroll
      for (int c = 0; c < 4; ++c) { or_[c] = f2bf(vr[c]); oa_[c] = f2bf(va[c]); }
      erb4[base + i] = or_;
      eab4[base + i] = oa_;
    }
    return;
  }
  if (blockIdx.x >= 513) {                          // time features for batch b
    int b = blockIdx.x - 513;
    float* tds = shf;
    int* xs = (int*)(shf + 4096);
    const f32x4* tp = (const f32x4*)(args.td + (size_t)b * 4096);
    const i32x4* xp = (const i32x4*)(args.x + (size_t)b * 4096);
    for (int j = t; j < 1024; j += 256) {
      f32x4 v = tp[j];
#pragma unroll
      for (int c = 0; c < 4; ++c) v[c] = fmaxf(v[c], 0.f);
      *(f32x4*)&tds[j * 4] = v;
      *(i32x4*)&xs[j * 4] = xp[j];
    }
    __syncthreads();
    if (t < 64) {
      int lane = t;
      float s = 0.f;
      for (int i = 0; i < 64; ++i) s += tds[lane * 64 + i];
      float pre = s;
#pragma unroll
      for (int off = 1; off < 64; off <<= 1) {
        float n2 = __shfl_up(pre, off, 64);
        if (lane >= off) pre += n2;
      }
      float a = pre - s;                            // exclusive prefix
      float am = 0.f; int anyv = 0;
      for (int i = 0; i < 64; ++i) {
        a += tds[lane * 64 + i];
        tds[lane * 64 + i] = a;                     // overwrite with cumsum
        if (xs[lane * 64 + i] != 0) { am = fmaxf(am, a); anyv = 1; }
      }
      float prev = __shfl_up(am, 1, 64);
      args.bin_rel[b * 64 + lane] = (lane == 0) ? 0.f : fmaxf(am - prev, 0.f);
      args.bin_mask[b * 64 + lane] = anyv;
      unsigned long long bal = __ballot(anyv != 0);
      if (lane == 0) args.last_idx[b] = max(__popcll(bal) - 1, 0);
    }
    __syncthreads();
    float* out = args.abs_t + (size_t)b * 4096;
    for (int j = t; j < 1024; j += 256)
      *(f32x4*)&out[j * 4] = *(const f32x4*)&tds[j * 4];
    return;
  }
  // weight transpose-pack
  float (*tile)[65] = (float(*)[65])shf;
  int mat = blockIdx.x >> 6;
  int tl = blockIdx.x & 63;
  const float* W = args.s[mat];
  unsigned short* Wt = args.d[mat];
  int n0 = (tl & 7) << 6, k0 = (tl >> 3) << 6;
  int j = t & 63, i0 = t >> 6;
#pragma unroll
  for (int rr = 0; rr < 16; ++rr) {
    int i = rr * 4 + i0;
    tile[i][j] = W[(size_t)(k0 + i) * 512 + n0 + j];
  }
  __syncthreads();
#pragma unroll
  for (int rr = 0; rr < 16; ++rr) {
    int i = rr * 4 + i0;
    Wt[(size_t)(n0 + i) * 512 + k0 + j] = f2bf(tile[j][i]);
  }
}

// ---------------- h = ee[x] (0 if x==0) + er_bf[rb] + ea_bf[ab], bf16 out. 16 tok/block.
__global__ __launch_bounds__(256) void k_embed(const int* __restrict__ x, const float* __restrict__ td,
    const float* __restrict__ abs_t, const float* __restrict__ ee,
    const unsigned short* __restrict__ er_bf, const unsigned short* __restrict__ ea_bf,
    unsigned short* __restrict__ h) {
  int t = threadIdx.x;
  int lane = t & 63;
  int c0 = lane * 8;
#pragma unroll
  for (int it = 0; it < 4; ++it) {
    int tok = blockIdx.x * 16 + it * 4 + (t >> 6);
    int xi = x[tok];
    int rb = (int)td[tok]; rb = min(max(rb, 0), 999);
    int ab = (int)abs_t[tok]; ab = min(max(ab, 0), 999);
    bf16x8 rv = *(const bf16x8*)(er_bf + (size_t)rb * 512 + c0);
    bf16x8 av = *(const bf16x8*)(ea_bf + (size_t)ab * 512 + c0);
    float sf[8];
#pragma unroll
    for (int i = 0; i < 8; ++i)
      sf[i] = bf2f((unsigned short)rv[i]) + bf2f((unsigned short)av[i]);
    if (xi != 0) {
      const f32x4* pe = (const f32x4*)(ee + (size_t)xi * 512 + c0);
      f32x4 e0 = pe[0], e1 = pe[1];
#pragma unroll
      for (int i = 0; i < 4; ++i) { sf[i] += e0[i]; sf[4 + i] += e1[i]; }
    }
    bf16x8 o;
#pragma unroll
    for (int i = 0; i < 8; ++i) o[i] = (short)f2bf(sf[i]);
    *(bf16x8*)(h + (size_t)tok * 512 + c0) = o;
  }
}

// ---------------- swizzle helpers
DEVI bf16x8 lds_frag32(const unsigned short* buf, int r, int g) {
  int sr = r >> 1;
  int slot = (((r & 1) << 2) | g) ^ (sr & 7);
  return *(const bf16x8*)&buf[sr * 64 + slot * 8];
}
DEVI bf16x8 lds_frag64(const unsigned short* buf, int row, int c) {
  return *(const bf16x8*)&buf[row * 64 + ((c ^ (row & 7)) << 3)];
}

// ---------------- big GEMM (QKV): 128x256 tile, 8 waves of 64x64 (r11 best: 59.5us).
__global__ __launch_bounds__(512, 4) void k_gemm256(const unsigned short* __restrict__ A,
    const unsigned short* __restrict__ Wt, const float* __restrict__ bias,
    unsigned short* __restrict__ Cout, int N, int tiles_n) {
  __shared__ unsigned short As[128 * 64];   // 16 KB
  __shared__ unsigned short Bs[256 * 64];   // 32 KB
  int bid = blockIdx.x;
  { int q = (int)gridDim.x >> 3; bid = (bid & 7) * q + (bid >> 3); }  // grid %8==0
  int by = bid / tiles_n, bx = bid % tiles_n;
  int m0 = by << 7, n0 = bx << 8;
  int t = threadIdx.x;
  int lane = t & 63, w = t >> 6;
  int wm = w >> 2, wn = w & 3;
  int l15 = lane & 15, l4 = lane >> 4;

  f32x4 acc[4][4] = {};
  for (int k0 = 0; k0 < 512; k0 += 64) {
    __syncthreads();
#pragma unroll
    for (int l = 0; l < 2; ++l) {
      int pos = l * 512 + t;
      int row = pos >> 3, g = (pos & 7) ^ (row & 7);
      GLOAD_LDS16(&A[(size_t)(m0 + row) * 512 + k0 + g * 8], &As[pos * 8]);
    }
#pragma unroll
    for (int l = 0; l < 4; ++l) {
      int pos = l * 512 + t;
      int row = pos >> 3, g = (pos & 7) ^ (row & 7);
      GLOAD_LDS16(&Wt[(size_t)(n0 + row) * 512 + k0 + g * 8], &Bs[pos * 8]);
    }
    __syncthreads();
#pragma unroll
    for (int ks = 0; ks < 2; ++ks) {
      bf16x8 af[4], bb[4];
#pragma unroll
      for (int i = 0; i < 4; ++i) {
        af[i] = lds_frag64(As, wm * 64 + i * 16 + l15, ks * 4 + l4);
        bb[i] = lds_frag64(Bs, wn * 64 + i * 16 + l15, ks * 4 + l4);
      }
      __builtin_amdgcn_s_setprio(1);
#pragma unroll
      for (int i = 0; i < 4; ++i)
#pragma unroll
        for (int j = 0; j < 4; ++j)
          acc[i][j] = __builtin_amdgcn_mfma_f32_16x16x32_bf16(af[i], bb[j], acc[i][j], 0, 0, 0);
      __builtin_amdgcn_s_setprio(0);
    }
  }
#pragma unroll
  for (int i = 0; i < 4; ++i) {
    int rowb = m0 + wm * 64 + i * 16 + (l4 << 2);
#pragma unroll
    for (int j = 0; j < 4; ++j) {
      int col = n0 + wn * 64 + j * 16 + l15;
      float bv = bias[col];
#pragma unroll
      for (int r = 0; r < 4; ++r)
        Cout[(size_t)(rowb + r) * N + col] = f2bf(acc[i][j][r] + bv);
    }
  }
}

// ---------------- fused out-proj + LN + masked pool: BM=128, BN=512, BK=32 (r10 best).
__global__ __launch_bounds__(512, 2) void k_oproj(const unsigned short* __restrict__ ctx,
    const unsigned short* __restrict__ WoT, const float* __restrict__ bo,
    const int* __restrict__ x, const float* __restrict__ g, const float* __restrict__ bt,
    unsigned short* __restrict__ bin_repr) {
  __shared__ unsigned short ldsA[4][128 * 32];
  __shared__ unsigned short ldsB[2][512 * 32];
  int bid = blockIdx.x;
  { int q = (int)gridDim.x >> 3; bid = (bid & 7) * q + (bid >> 3); }
  int m0 = bid << 7;
  int t = threadIdx.x;
  int lane = t & 63, w = t >> 6;
  int l15 = lane & 15, l4 = lane >> 4;

  auto stageA = [&](int kt) {
    int k0 = kt << 5;
    unsigned short* dst = &ldsA[kt & 3][0];
    int pos = t;
    int sr = pos >> 3, slot = pos & 7;
    int gp = slot ^ (sr & 7);
    int row = sr * 2 + (gp >> 2);
    GLOAD_LDS16(&ctx[(size_t)(m0 + row) * 512 + k0 + (gp & 3) * 8], dst + pos * 8);
  };
  auto stageB = [&](int kt) {
    int k0 = kt << 5;
    unsigned short* dst = &ldsB[kt & 1][0];
#pragma unroll
    for (int l = 0; l < 4; ++l) {
      int pos = l * 512 + t;
      int sr = pos >> 3, slot = pos & 7;
      int gp = slot ^ (sr & 7);
      int row = sr * 2 + (gp >> 2);
      GLOAD_LDS16(&WoT[(size_t)row * 512 + k0 + (gp & 3) * 8], dst + pos * 8);
    }
  };

  f32x4 acc[8][4] = {};
  stageB(0); stageA(0); stageA(1); stageA(2); stageB(1);

  for (int kt = 0; kt < 16; ++kt) {
    if (kt == 0)      asm volatile("s_waitcnt vmcnt(6)" ::: "memory");
    else if (kt < 14) asm volatile("s_waitcnt vmcnt(1)" ::: "memory");
    else              asm volatile("s_waitcnt vmcnt(0)" ::: "memory");
    __builtin_amdgcn_s_barrier();
    const unsigned short* As = &ldsA[kt & 3][0];
    const unsigned short* Bs = &ldsB[kt & 1][0];

    bf16x8 af[4], bb[4];
#pragma unroll
    for (int i = 0; i < 4; ++i) af[i] = lds_frag32(As, i * 16 + l15, l4);
#pragma unroll
    for (int j = 0; j < 4; ++j) bb[j] = lds_frag32(Bs, w * 64 + j * 16 + l15, l4);
    if (kt >= 1 && kt <= 14) stageB(kt + 1);
    __builtin_amdgcn_s_barrier();
    asm volatile("s_waitcnt lgkmcnt(0)" ::: "memory");
    __builtin_amdgcn_sched_barrier(0);
    __builtin_amdgcn_s_setprio(1);
#pragma unroll
    for (int i = 0; i < 4; ++i)
#pragma unroll
      for (int j = 0; j < 4; ++j)
        acc[i][j] = __builtin_amdgcn_mfma_f32_16x16x32_bf16(af[i], bb[j], acc[i][j], 0, 0, 0);
    __builtin_amdgcn_s_setprio(0);

    bf16x8 ah[4];
#pragma unroll
    for (int i = 0; i < 4; ++i) ah[i] = lds_frag32(As, 64 + i * 16 + l15, l4);
    if (kt <= 12) stageA(kt + 3);
    __builtin_amdgcn_s_barrier();
    asm volatile("s_waitcnt lgkmcnt(0)" ::: "memory");
    __builtin_amdgcn_sched_barrier(0);
    __builtin_amdgcn_s_setprio(1);
#pragma unroll
    for (int i = 0; i < 4; ++i)
#pragma unroll
      for (int j = 0; j < 4; ++j)
        acc[4 + i][j] = __builtin_amdgcn_mfma_f32_16x16x32_bf16(ah[i], bb[j], acc[4 + i][j], 0, 0, 0);
    __builtin_amdgcn_s_setprio(0);
  }

  __syncthreads();
  float* red   = (float*)&ldsA[0][0];    // [128][9]
  float* meanL = red + 128 * 9;
  float* rstdL = meanL + 128;
  int*   valL  = (int*)(rstdL + 128);
  int*   cntL  = valL + 128;

  int cols[4]; float bov[4], gv[4], bv[4];
#pragma unroll
  for (int j = 0; j < 4; ++j) {
    cols[j] = w * 64 + j * 16 + l15;
    bov[j] = bo[cols[j]]; gv[j] = g[cols[j]]; bv[j] = bt[cols[j]];
  }
  if (t < 128) {
    int v = (x[m0 + t] != 0) ? 1 : 0;
    valL[t] = v;
    unsigned long long bal = __ballot(v != 0);
    if ((t & 63) == 0) cntL[t >> 6] = __popcll(bal);
  }
#pragma unroll
  for (int i = 0; i < 8; ++i)
#pragma unroll
    for (int r = 0; r < 4; ++r) {
      float s = (acc[i][0][r] + bov[0]) + (acc[i][1][r] + bov[1]) +
                (acc[i][2][r] + bov[2]) + (acc[i][3][r] + bov[3]);
#pragma unroll
      for (int off = 1; off < 16; off <<= 1) s += __shfl_xor(s, off, 64);
      if (l15 == 0) red[(i * 16 + l4 * 4 + r) * 9 + w] = s;
    }
  __syncthreads();
  if (t < 128) {
    float m = 0.f;
#pragma unroll
    for (int ww = 0; ww < 8; ++ww) m += red[t * 9 + ww];
    meanL[t] = m * (1.f / 512.f);
  }
  __syncthreads();
#pragma unroll
  for (int i = 0; i < 8; ++i)
#pragma unroll
    for (int r = 0; r < 4; ++r) {
      float m = meanL[i * 16 + l4 * 4 + r];
      float s = 0.f;
#pragma unroll
      for (int j = 0; j < 4; ++j) { float d = acc[i][j][r] + bov[j] - m; s += d * d; }
#pragma unroll
      for (int off = 1; off < 16; off <<= 1) s += __shfl_xor(s, off, 64);
      if (l15 == 0) red[(i * 16 + l4 * 4 + r) * 9 + w] = s;
    }
  __syncthreads();
  if (t < 128) {
    float vsum = 0.f;
#pragma unroll
    for (int ww = 0; ww < 8; ++ww) vsum += red[t * 9 + ww];
    rstdL[t] = rsqrtf(vsum * (1.f / 512.f) + 1e-5f);
  }
  __syncthreads();
  float p0[4] = {0.f, 0.f, 0.f, 0.f}, p1[4] = {0.f, 0.f, 0.f, 0.f};
#pragma unroll
  for (int i = 0; i < 8; ++i)
#pragma unroll
    for (int r = 0; r < 4; ++r) {
      int row = i * 16 + l4 * 4 + r;
      if (valL[row]) {
        float m = meanL[row], rs = rstdL[row];
#pragma unroll
        for (int j = 0; j < 4; ++j) {
          float y = (acc[i][j][r] + bov[j] - m) * rs * gv[j] + bv[j];
          if (i < 4) p0[j] += y; else p1[j] += y;
        }
      }
    }
#pragma unroll
  for (int j = 0; j < 4; ++j) {
    p0[j] += __shfl_xor(p0[j], 16, 64); p0[j] += __shfl_xor(p0[j], 32, 64);
    p1[j] += __shfl_xor(p1[j], 16, 64); p1[j] += __shfl_xor(p1[j], 32, 64);
  }
  float d0 = 1.f / fmaxf((float)cntL[0], 1.f);
  float d1 = 1.f / fmaxf((float)cntL[1], 1.f);
  if (l4 == 0) {
    int binr = (m0 >> 6);
#pragma unroll
    for (int j = 0; j < 4; ++j) {
      bin_repr[(size_t)binr * 512 + cols[j]]       = f2bf(p0[j] * d0);
      bin_repr[(size_t)(binr + 1) * 512 + cols[j]] = f2bf(p1[j] * d1);
    }
  }
}

// ---------------- small GEMM (inter qkv2): 128x128 tile, reg-staged padded LDS.
__global__ __launch_bounds__(256) void k_gemm(const unsigned short* __restrict__ A,
    const unsigned short* __restrict__ Wt, const float* __restrict__ bias,
    unsigned short* __restrict__ Cout, int N, int tiles_n) {
  __shared__ unsigned short As[128 * 72];
  __shared__ unsigned short Bs[128 * 72];
  int bx = blockIdx.x % tiles_n;
  int by = blockIdx.x / tiles_n;
  int m0 = by << 7, n0 = bx << 7;
  int t = threadIdx.x;
  int lane = t & 63, w = t >> 6;
  int wm = w >> 1, wn = w & 1;
  f32x4 acc[4][4] = {};
  for (int k0 = 0; k0 < 512; k0 += 64) {
    __syncthreads();
#pragma unroll
    for (int i = 0; i < 4; ++i) {
      int idx = t + i * 256;
      int row = idx >> 3, seg = idx & 7;
      *(bf16x8*)&As[row * 72 + seg * 8] = *(const bf16x8*)&A[(size_t)(m0 + row) * 512 + k0 + seg * 8];
      *(bf16x8*)&Bs[row * 72 + seg * 8] = *(const bf16x8*)&Wt[(size_t)(n0 + row) * 512 + k0 + seg * 8];
    }
    __syncthreads();
#pragma unroll
    for (int ks = 0; ks < 2; ++ks) {
      bf16x8 af[4], bb[4];
#pragma unroll
      for (int i = 0; i < 4; ++i) {
        af[i] = *(const bf16x8*)&As[(wm * 64 + i * 16 + (lane & 15)) * 72 + ks * 32 + (lane >> 4) * 8];
        bb[i] = *(const bf16x8*)&Bs[(wn * 64 + i * 16 + (lane & 15)) * 72 + ks * 32 + (lane >> 4) * 8];
      }
#pragma unroll
      for (int i = 0; i < 4; ++i)
#pragma unroll
        for (int j = 0; j < 4; ++j)
          acc[i][j] = __builtin_amdgcn_mfma_f32_16x16x32_bf16(af[i], bb[j], acc[i][j], 0, 0, 0);
    }
  }
#pragma unroll
  for (int i = 0; i < 4; ++i) {
    int rowb = m0 + wm * 64 + i * 16 + ((lane >> 4) << 2);
#pragma unroll
    for (int j = 0; j < 4; ++j) {
      int col = n0 + wn * 64 + j * 16 + (lane & 15);
      float bv = bias[col];
#pragma unroll
      for (int r = 0; r < 4; ++r)
        Cout[(size_t)(rowb + r) * N + col] = f2bf(acc[i][j][r] + bv);
    }
  }
}

// ---------------- intra attention; block = 4 heads of one 64-token bin (2 blocks/bin).
__global__ __launch_bounds__(256) void k_attn(const unsigned short* __restrict__ qkv,
    const float* __restrict__ td, const int* __restrict__ validv,
    const float* __restrict__ temb, unsigned short* __restrict__ ctx) {
  __shared__ float bias_s[4][64];
  __shared__ int valid_s[64];
  __shared__ unsigned short P_s[4][64][72];
  __shared__ unsigned short Vt_s[4][64][72];
  int blk = blockIdx.x >> 1, hg = blockIdx.x & 1;
  int t = threadIdx.x, hl = t >> 6, lane = t & 63;
  int h = hg * 4 + hl;
  size_t base = (size_t)blk * 64;
  if (t < 64) {
    valid_s[t] = (validv[base + t] != 0) ? 1 : 0;
    int tb = (int)td[base + t];
    tb = min(max(tb, 0), 999);
#pragma unroll
    for (int hh = 0; hh < 4; ++hh) bias_s[hh][t] = temb[tb * 8 + hg * 4 + hh];
  }
  {
    const unsigned short* vp = qkv + (base + lane) * 1536 + 1024 + h * 64;
#pragma unroll
    for (int f8 = 0; f8 < 8; ++f8) {
      bf16x8 v8 = *(const bf16x8*)(vp + f8 * 8);
#pragma unroll
      for (int j = 0; j < 8; ++j) Vt_s[hl][f8 * 8 + j][lane] = (unsigned short)v8[j];
    }
  }
  __syncthreads();
  bf16x8 qa[2][4], kb[2][4];
#pragma unroll
  for (int ks = 0; ks < 2; ++ks)
#pragma unroll
    for (int i = 0; i < 4; ++i) {
      int row = i * 16 + (lane & 15);
      int kk = ks * 32 + (lane >> 4) * 8;
      qa[ks][i] = *(const bf16x8*)&qkv[(base + row) * 1536 + h * 64 + kk];
      kb[ks][i] = *(const bf16x8*)&qkv[(base + row) * 1536 + 512 + h * 64 + kk];
    }
  f32x4 acc[4][4] = {};
#pragma unroll
  for (int ks = 0; ks < 2; ++ks)
#pragma unroll
    for (int i = 0; i < 4; ++i)
#pragma unroll
      for (int j = 0; j < 4; ++j)
        acc[i][j] = __builtin_amdgcn_mfma_f32_16x16x32_bf16(qa[ks][i], kb[ks][j], acc[i][j], 0, 0, 0);
  float invs[4][4];
#pragma unroll
  for (int i = 0; i < 4; ++i) {
#pragma unroll
    for (int r = 0; r < 4; ++r) {
      float sv[4];
#pragma unroll
      for (int j = 0; j < 4; ++j) {
        int key = j * 16 + (lane & 15);
        float s = acc[i][j][r] * 0.125f;
        sv[j] = valid_s[key] ? (s + bias_s[hl][key]) : -1e9f;
      }
      float m = fmaxf(fmaxf(sv[0], sv[1]), fmaxf(sv[2], sv[3]));
#pragma unroll
      for (int off = 1; off < 16; off <<= 1) m = fmaxf(m, __shfl_xor(m, off, 64));
      float p[4], sum = 0.f;
#pragma unroll
      for (int j = 0; j < 4; ++j) { p[j] = __expf(sv[j] - m); sum += p[j]; }
#pragma unroll
      for (int off = 1; off < 16; off <<= 1) sum += __shfl_xor(sum, off, 64);
      invs[i][r] = 1.f / sum;
      int row = i * 16 + ((lane >> 4) << 2) + r;
#pragma unroll
      for (int j = 0; j < 4; ++j) P_s[hl][row][j * 16 + (lane & 15)] = f2bf(p[j]);
    }
  }
  __syncthreads();
  f32x4 acc2[4][4] = {};
#pragma unroll
  for (int ks = 0; ks < 2; ++ks) {
    bf16x8 pa[4], vb[4];
    int kk = ks * 32 + (lane >> 4) * 8;
#pragma unroll
    for (int i = 0; i < 4; ++i) {
      pa[i] = *(const bf16x8*)&P_s[hl][i * 16 + (lane & 15)][kk];
      vb[i] = *(const bf16x8*)&Vt_s[hl][i * 16 + (lane & 15)][kk];
    }
#pragma unroll
    for (int i = 0; i < 4; ++i)
#pragma unroll
      for (int j = 0; j < 4; ++j)
        acc2[i][j] = __builtin_amdgcn_mfma_f32_16x16x32_bf16(pa[i], vb[j], acc2[i][j], 0, 0, 0);
  }
  unsigned short* scr = &Vt_s[hl][0][0];
#pragma unroll
  for (int i = 0; i < 4; ++i)
#pragma unroll
    for (int j = 0; j < 4; ++j)
#pragma unroll
      for (int r = 0; r < 4; ++r)
        scr[(i * 16 + ((lane >> 4) << 2) + r) * 72 + j * 16 + (lane & 15)] =
            f2bf(acc2[i][j][r] * invs[i][r]);
#pragma unroll
  for (int p = 0; p < 8; ++p) {
    int rl = p * 8 + (lane >> 3);
    bf16x8 vv = *(const bf16x8*)&scr[rl * 72 + (lane & 7) * 8];
    *(bf16x8*)&ctx[(base + rl) * 512 + h * 64 + (lane & 7) * 8] = vv;
  }
}

// ---------------- fused inter attention + last-row proj + LN + MLP + sigmoid. 8 blocks.
__global__ __launch_bounds__(512) void k_inter2(const unsigned short* __restrict__ qkv,
    const float* __restrict__ brel, const int* __restrict__ bmask,
    const float* __restrict__ temb, const int* __restrict__ last_idx,
    const float* __restrict__ Wo, const float* __restrict__ bo,
    const float* __restrict__ g, const float* __restrict__ bt,
    const float* __restrict__ w1, const float* __restrict__ b1,
    const float* __restrict__ w2, const float* __restrict__ b2,
    float* __restrict__ outp) {
  __shared__ unsigned short Vt[8][64][72];
  __shared__ unsigned short PsCtx[8 * 64 * 72];     // Ps slots, then ctx[64][520] overlay
  __shared__ float bias_s[8][64];
  __shared__ int valid_s[64];
  __shared__ float rowf[512];
  __shared__ float redA[8];
  __shared__ float redB[8];
  int b = blockIdx.x;
  int t = threadIdx.x, w = t >> 6, lane = t & 63;
  int l15 = lane & 15, l4 = lane >> 4;
  size_t base = (size_t)b * 64;

  if (t < 64) {
    valid_s[t] = (bmask[base + t] != 0) ? 1 : 0;
    int tb = (int)brel[base + t];
    tb = min(max(tb, 0), 999);
#pragma unroll
    for (int hh = 0; hh < 8; ++hh) bias_s[hh][t] = temb[tb * 8 + hh];
  }
  {
    const unsigned short* vp = qkv + (base + lane) * 1536 + 1024 + w * 64;
#pragma unroll
    for (int f8 = 0; f8 < 8; ++f8) {
      bf16x8 v8 = *(const bf16x8*)(vp + f8 * 8);
#pragma unroll
      for (int j = 0; j < 8; ++j) Vt[w][f8 * 8 + j][lane] = (unsigned short)v8[j];
    }
  }
  __syncthreads();

  bf16x8 qa[2][4], kb[2][4];
#pragma unroll
  for (int ks = 0; ks < 2; ++ks)
#pragma unroll
    for (int i = 0; i < 4; ++i) {
      int row = i * 16 + l15;
      int kk = ks * 32 + l4 * 8;
      qa[ks][i] = *(const bf16x8*)&qkv[(base + row) * 1536 + w * 64 + kk];
      kb[ks][i] = *(const bf16x8*)&qkv[(base + row) * 1536 + 512 + w * 64 + kk];
    }
  f32x4 acc[4][4] = {};
#pragma unroll
  for (int ks = 0; ks < 2; ++ks)
#pragma unroll
    for (int i = 0; i < 4; ++i)
#pragma unroll
      for (int j = 0; j < 4; ++j)
        acc[i][j] = __builtin_amdgcn_mfma_f32_16x16x32_bf16(qa[ks][i], kb[ks][j], acc[i][j], 0, 0, 0);

  unsigned short* Psw = &PsCtx[w * 64 * 72];
  float invs[4][4];
#pragma unroll
  for (int i = 0; i < 4; ++i) {
#pragma unroll
    for (int r = 0; r < 4; ++r) {
      float sv[4];
#pragma unroll
      for (int j = 0; j < 4; ++j) {
        int key = j * 16 + l15;
        float s = acc[i][j][r] * 0.125f;
        sv[j] = valid_s[key] ? (s + bias_s[w][key]) : -1e9f;
      }
      float m = fmaxf(fmaxf(sv[0], sv[1]), fmaxf(sv[2], sv[3]));
#pragma unroll
      for (int off = 1; off < 16; off <<= 1) m = fmaxf(m, __shfl_xor(m, off, 64));
      float p[4], sum = 0.f;
#pragma unroll
      for (int j = 0; j < 4; ++j) { p[j] = __expf(sv[j] - m); sum += p[j]; }
#pragma unroll
      for (int off = 1; off < 16; off <<= 1) sum += __shfl_xor(sum, off, 64);
      invs[i][r] = 1.f / sum;
      int row = i * 16 + l4 * 4 + r;
#pragma unroll
      for (int j = 0; j < 4; ++j) Psw[row * 72 + j * 16 + l15] = f2bf(p[j]);
    }
  }

  f32x4 acc2[4][4] = {};
#pragma unroll
  for (int ks = 0; ks < 2; ++ks) {
    bf16x8 pa[4], vb[4];
    int kk = ks * 32 + l4 * 8;
#pragma unroll
    for (int i = 0; i < 4; ++i) {
      pa[i] = *(const bf16x8*)&Psw[(i * 16 + l15) * 72 + kk];
      vb[i] = *(const bf16x8*)&Vt[w][i * 16 + l15][kk];
    }
#pragma unroll
    for (int i = 0; i < 4; ++i)
#pragma unroll
      for (int j = 0; j < 4; ++j)
        acc2[i][j] = __builtin_amdgcn_mfma_f32_16x16x32_bf16(pa[i], vb[j], acc2[i][j], 0, 0, 0);
  }

  __syncthreads();
  unsigned short* ctxl = PsCtx;                     // ctx[64][520] overlay
#pragma unroll
  for (int i = 0; i < 4; ++i)
#pragma unroll
    for (int j = 0; j < 4; ++j)
#pragma unroll
      for (int r = 0; r < 4; ++r)
        ctxl[(i * 16 + l4 * 4 + r) * 520 + w * 64 + j * 16 + l15] =
            f2bf(acc2[i][j][r] * invs[i][r]);
  __syncthreads();

  // proj of row last_idx: out[n] = bo[n] + sum_k ctx[k] * Wo[k][n]  (Wo f32 k-major)
  int li = last_idx[b];
  const unsigned short* crow = &ctxl[li * 520];
  float pacc = bo[t];
  for (int k = 0; k < 512; k += 4) {
    float c0 = bf2f(crow[k]),     c1 = bf2f(crow[k + 1]);
    float c2 = bf2f(crow[k + 2]), c3 = bf2f(crow[k + 3]);
    pacc += c0 * Wo[(size_t)k * 512 + t]       + c1 * Wo[(size_t)(k + 1) * 512 + t]
          + c2 * Wo[(size_t)(k + 2) * 512 + t] + c3 * Wo[(size_t)(k + 3) * 512 + t];
  }
  // LN over the 512-vec
  float s = pacc;
#pragma unroll
  for (int off = 1; off < 64; off <<= 1) s += __shfl_xor(s, off, 64);
  if (lane == 0) redA[w] = s;
  __syncthreads();
  float tot = 0.f;
#pragma unroll
  for (int ww = 0; ww < 8; ++ww) tot += redA[ww];
  float mean = tot * (1.f / 512.f);
  float d = pacc - mean;
  float vs = d * d;
#pragma unroll
  for (int off = 1; off < 64; off <<= 1) vs += __shfl_xor(vs, off, 64);
  if (lane == 0) redB[w] = vs;
  __syncthreads();
  float vtot = 0.f;
#pragma unroll
  for (int ww = 0; ww < 8; ++ww) vtot += redB[ww];
  float rstd = rsqrtf(vtot * (1.f / 512.f) + 1e-5f);
  rowf[t] = d * rstd * g[t] + bt[t];
  __syncthreads();
  float hv = 0.f;
  if (t < 256) {
    float a1 = b1[t];
    for (int k = 0; k < 512; ++k) a1 += rowf[k] * w1[(size_t)k * 256 + t];
    hv = fmaxf(a1, 0.f) * w2[t];
  }
#pragma unroll
  for (int off = 1; off < 64; off <<= 1) hv += __shfl_xor(hv, off, 64);
  if (lane == 0) redA[w] = hv;
  __syncthreads();
  if (t == 0) {
    float o = redA[0] + redA[1] + redA[2] + redA[3] + redA[4] + redA[5] + redA[6] + redA[7] + b2[0];
    outp[b] = 1.f / (1.f + __expf(-o));
  }
}

extern "C" void kernel_launch(void* const* d_in, const int* in_sizes, int n_in,
                              void* d_out, int out_size, void* d_ws, size_t ws_size,
                              hipStream_t stream) {
  const int*   x    = (const int*)d_in[0];
  const float* td   = (const float*)d_in[1];
  const float* ee   = (const float*)d_in[2];
  const float* er   = (const float*)d_in[3];
  const float* ea   = (const float*)d_in[4];
  const float* iq_w = (const float*)d_in[5];  const float* iq_b = (const float*)d_in[6];
  const float* ik_w = (const float*)d_in[7];  const float* ik_b = (const float*)d_in[8];
  const float* iv_w = (const float*)d_in[9];  const float* iv_b = (const float*)d_in[10];
  const float* io_w = (const float*)d_in[11]; const float* io_b = (const float*)d_in[12];
  const float* eq_w = (const float*)d_in[13]; const float* eq_b = (const float*)d_in[14];
  const float* ek_w = (const float*)d_in[15]; const float* ek_b = (const float*)d_in[16];
  const float* ev_w = (const float*)d_in[17]; const float* ev_b = (const float*)d_in[18];
  const float* eo_w = (const float*)d_in[19]; const float* eo_b = (const float*)d_in[20];
  const float* i_temb = (const float*)d_in[21];
  const float* e_temb = (const float*)d_in[22];
  const float* i_g  = (const float*)d_in[23]; const float* i_bt = (const float*)d_in[24];
  const float* e_g  = (const float*)d_in[25]; const float* e_bt = (const float*)d_in[26];
  const float* w1   = (const float*)d_in[27]; const float* b1   = (const float*)d_in[28];
  const float* w2   = (const float*)d_in[29]; const float* b2   = (const float*)d_in[30];

  char* ws = (char*)d_ws;
  size_t off = 0;
  auto alloc = [&](size_t nb) { size_t r = off; off += (nb + 255) & ~(size_t)255; return r; };
  float* abs_t    = (float*)(ws + alloc((size_t)32768 * 4));
  float* bin_rel  = (float*)(ws + alloc(512 * 4));
  int*   bin_mask = (int*)(ws + alloc(512 * 4));
  int*   last_idx = (int*)(ws + alloc(64));
  unsigned short* wqkv_i = (unsigned short*)(ws + alloc((size_t)1536 * 512 * 2));
  unsigned short* wo_i   = (unsigned short*)(ws + alloc((size_t)512 * 512 * 2));
  unsigned short* wqkv_e = (unsigned short*)(ws + alloc((size_t)1536 * 512 * 2));
  unsigned short* wo_e   = (unsigned short*)(ws + alloc((size_t)512 * 512 * 2));
  float* bqkv_i = (float*)(ws + alloc(1536 * 4));
  float* bqkv_e = (float*)(ws + alloc(1536 * 4));
  unsigned short* er_bf = (unsigned short*)(ws + alloc((size_t)1000 * 512 * 2));
  unsigned short* ea_bf = (unsigned short*)(ws + alloc((size_t)1000 * 512 * 2));
  unsigned short* hbuf = (unsigned short*)(ws + alloc((size_t)32768 * 512 * 2));   // h, then ctx
  unsigned short* qkvbuf = (unsigned short*)(ws + alloc((size_t)32768 * 1536 * 2));
  unsigned short* bin_repr = (unsigned short*)(ws + alloc((size_t)512 * 512 * 2));
  unsigned short* qkv2 = (unsigned short*)(ws + alloc((size_t)512 * 1536 * 2));

  // 1. pack weights + bias concats + time features + er/ea bf16 tables (one launch)
  TPackArgs tp;
  tp.s[0] = iq_w; tp.d[0] = wqkv_i;
  tp.s[1] = ik_w; tp.d[1] = wqkv_i + (size_t)512 * 512;
  tp.s[2] = iv_w; tp.d[2] = wqkv_i + (size_t)1024 * 512;
  tp.s[3] = io_w; tp.d[3] = wo_i;
  tp.s[4] = eq_w; tp.d[4] = wqkv_e;
  tp.s[5] = ek_w; tp.d[5] = wqkv_e + (size_t)512 * 512;
  tp.s[6] = ev_w; tp.d[6] = wqkv_e + (size_t)1024 * 512;
  tp.s[7] = eo_w; tp.d[7] = wo_e;
  tp.bs[0] = iq_b; tp.bs[1] = ik_b; tp.bs[2] = iv_b;
  tp.bs[3] = eq_b; tp.bs[4] = ek_b; tp.bs[5] = ev_b;
  tp.bd[0] = bqkv_i; tp.bd[1] = bqkv_e;
  tp.td = td; tp.x = x;
  tp.abs_t = abs_t; tp.bin_rel = bin_rel; tp.bin_mask = bin_mask; tp.last_idx = last_idx;
  tp.er = er; tp.ea = ea; tp.er_bf = er_bf; tp.ea_bf = ea_bf;
  k_tpack8<<<649, 256, 0, stream>>>(tp);

  // 2. embeddings -> h
  k_embed<<<2048, 256, 0, stream>>>(x, td, abs_t, ee, er_bf, ea_bf, hbuf);

  // 3. intra path
  k_gemm256<<<256 * 6, 512, 0, stream>>>(hbuf, wqkv_i, bqkv_i, qkvbuf, 1536, 6);
  k_attn<<<1024, 256, 0, stream>>>(qkvbuf, td, x, i_temb, hbuf);                   // ctx -> hbuf
  k_oproj<<<256, 512, 0, stream>>>(hbuf, wo_i, io_b, x, i_g, i_bt, bin_repr);      // proj+LN+pool

  // 4. inter path: qkv2 GEMM, then fused attn+proj-row+LN+MLP+sigmoid
  k_gemm<<<4 * 12, 256, 0, stream>>>(bin_repr, wqkv_e, bqkv_e, qkv2, 1536, 12);
  k_inter2<<<8, 512, 0, stream>>>(qkv2, bin_rel, bin_mask, e_temb, last_idx,
                                  eo_w, eo_b, e_g, e_bt, w1, b1, w2, b2, (float*)d_out);
}